// Round 1
// 821.253 us; speedup vs baseline: 1.0727x; 1.0727x over previous
//
#include <hip/hip_runtime.h>
#include <cstdint>
#include <cstddef>

// Problem constants (fixed shapes from setup_inputs)
#define Tt 4096      // tokens = B*S
#define Hd 2048      // hidden
#define Fd 2048      // ffn
#define En 8         // experts
#define Rcap 9216    // 8192 assignments + 8*128 padding

typedef short bf16x8 __attribute__((ext_vector_type(8)));
typedef float f32x4 __attribute__((ext_vector_type(4)));
typedef unsigned int u32;
typedef u32 __attribute__((address_space(1))) gas_u32;
typedef u32 __attribute__((address_space(3))) las_u32;

__device__ __forceinline__ unsigned short f2bf(float f) {
    u32 u = __builtin_bit_cast(u32, f);
    u = (u + 0x7FFFu + ((u >> 16) & 1u)) >> 16;   // round-to-nearest-even
    return (unsigned short)u;
}
__device__ __forceinline__ float bf2f(unsigned short s) {
    return __builtin_bit_cast(float, ((u32)s) << 16);
}

// ---------------- Router: fp32 logits, softmax, top-2, renormalize ----------
__global__ __launch_bounds__(256) void router_kernel(
    const float* __restrict__ x, const float* __restrict__ gate,
    int* __restrict__ topi, float* __restrict__ topw)
{
    const int t = blockIdx.x;
    const float* xr = x + (size_t)t * Hd;
    float acc[En];
    #pragma unroll
    for (int e = 0; e < En; ++e) acc[e] = 0.f;
    for (int h = threadIdx.x; h < Hd; h += 256) {
        const float xv = xr[h];
        #pragma unroll
        for (int e = 0; e < En; ++e) acc[e] += xv * gate[e * Hd + h];
    }
    #pragma unroll
    for (int e = 0; e < En; ++e) {
        float v = acc[e];
        for (int d = 32; d > 0; d >>= 1) v += __shfl_down(v, d, 64);
        acc[e] = v;
    }
    __shared__ float red[En][4];
    const int lane = threadIdx.x & 63, wv = threadIdx.x >> 6;
    if (lane == 0) {
        #pragma unroll
        for (int e = 0; e < En; ++e) red[e][wv] = acc[e];
    }
    __syncthreads();
    if (threadIdx.x == 0) {
        float l[En];
        #pragma unroll
        for (int e = 0; e < En; ++e) l[e] = red[e][0] + red[e][1] + red[e][2] + red[e][3];
        float m = l[0];
        #pragma unroll
        for (int e = 1; e < En; ++e) m = fmaxf(m, l[e]);
        float p[En];
        #pragma unroll
        for (int e = 0; e < En; ++e) p[e] = expf(l[e] - m);
        int i1 = 0;
        #pragma unroll
        for (int e = 1; e < En; ++e) if (p[e] > p[i1]) i1 = e;
        int i2 = (i1 == 0) ? 1 : 0;
        #pragma unroll
        for (int e = 0; e < En; ++e) if (e != i1 && p[e] > p[i2]) i2 = e;
        const float s = p[i1] + p[i2];
        topi[2 * t] = i1; topi[2 * t + 1] = i2;
        topw[2 * t] = p[i1] / s; topw[2 * t + 1] = p[i2] / s;
    }
}

// ---------------- Expert assignment ----------------------------------------
__global__ void assign_kernel(const int* __restrict__ topi, int* __restrict__ cnt,
                              int* __restrict__ posbuf)
{
    const int idx = blockIdx.x * blockDim.x + threadIdx.x;
    if (idx >= Tt * 2) return;
    posbuf[idx] = atomicAdd(&cnt[topi[idx]], 1);
}

__global__ void scan_kernel(const int* __restrict__ cnt, int* __restrict__ off,
                            int* __restrict__ pcnt)
{
    if (threadIdx.x == 0 && blockIdx.x == 0) {
        int a = 0;
        for (int e = 0; e < En; ++e) {
            off[e] = a;
            const int pc = (cnt[e] + 127) & ~127;
            pcnt[e] = pc;
            a += pc;
        }
    }
}

// Gather x rows -> bf16 Xg (permuted by expert).
__global__ __launch_bounds__(256) void gather_kernel(
    const float* __restrict__ x, const int* __restrict__ topi,
    const int* __restrict__ off, const int* __restrict__ posbuf,
    unsigned short* __restrict__ Xg)
{
    const int entry = blockIdx.x;           // 0..8191
    const int t = entry >> 1;
    const int e = topi[entry];
    const int row = off[e] + posbuf[entry];
    const float4* src = (const float4*)(x + (size_t)t * Hd);
    const int i = threadIdx.x;              // 8 elems per thread
    const float4 a = src[2 * i], b = src[2 * i + 1];
    unsigned short o[8];
    o[0] = f2bf(a.x); o[1] = f2bf(a.y); o[2] = f2bf(a.z); o[3] = f2bf(a.w);
    o[4] = f2bf(b.x); o[5] = f2bf(b.y); o[6] = f2bf(b.z); o[7] = f2bf(b.w);
    ((uint4*)(Xg + (size_t)row * Hd))[i] = *(const uint4*)o;
}

// ---------------- Weight transpose + bf16 convert: [E][K][N] -> [E][N][K] ---
// 64x64 tiles; fp32 LDS with odd pad (2-way bank aliasing = free);
// 32B-per-lane output stores (was 2B/lane).
__global__ __launch_bounds__(256) void transpose_kernel(
    const float* __restrict__ w1s, const float* __restrict__ w3s,
    const float* __restrict__ w2s, unsigned short* __restrict__ w1T,
    unsigned short* __restrict__ w3T, unsigned short* __restrict__ w2T)
{
    __shared__ float tile[64][65];
    const int z = blockIdx.z, tensor = z >> 3, e = z & 7;
    const float* src = (tensor == 0) ? w1s : (tensor == 1) ? w3s : w2s;
    unsigned short* dst = (tensor == 0) ? w1T : (tensor == 1) ? w3T : w2T;
    const int c0 = blockIdx.x * 64, r0 = blockIdx.y * 64;
    const size_t base = (size_t)e * 2048 * 2048;

    // Load: thread -> src row r (0..63), 16 consecutive cols starting cg.
    {
        const int r = threadIdx.x >> 2, cg = (threadIdx.x & 3) * 16;
        const float4* s4 = (const float4*)(src + base + (size_t)(r0 + r) * 2048 + c0 + cg);
        #pragma unroll
        for (int i = 0; i < 4; ++i) {
            const float4 v = s4[i];
            float* tr = &tile[r][cg + 4 * i];
            tr[0] = v.x; tr[1] = v.y; tr[2] = v.z; tr[3] = v.w;
        }
    }
    __syncthreads();
    // Store: thread -> dst row (c0+ny), 16 consecutive k starting r0+k0.
    {
        const int ny = threadIdx.x >> 2, k0 = (threadIdx.x & 3) * 16;
        __align__(16) unsigned short o[16];
        #pragma unroll
        for (int j = 0; j < 16; ++j) o[j] = f2bf(tile[k0 + j][ny]);
        unsigned short* d = dst + base + (size_t)(c0 + ny) * 2048 + r0 + k0;
        *(uint4*)(d) = *(const uint4*)(o);
        *(uint4*)(d + 8) = *(const uint4*)(o + 8);
    }
}

// ---------------- GEMM: C[M,N] = A[M,K] * B[N,K]^T  (both K-major, bf16) ----
// m97 structure: 128x128 tile, BK=64, global_load_lds width 16, XOR-swizzled
// LDS chunk layout so ds_read_b128 fragment loads are bank-conflict-free.
// Grid y = flat padded-row-tile (exact, no empty blocks); expert found via off[].
// EPI==0: dual bf16 output (z=0 -> B=w1T,C=H1; z=1 -> B=w3T,C=H3).
// EPI==1: fp32 store of per-row expert output into Yg (merged later; no atomics).
template <int EPI>
__global__ __launch_bounds__(256) void gemm_kernel(
    const unsigned short* __restrict__ Ab,
    const unsigned short* __restrict__ Bb0,
    const unsigned short* __restrict__ Bb1,
    unsigned short* __restrict__ C0,
    unsigned short* __restrict__ C1,
    float* __restrict__ Cf,
    const int* __restrict__ off, const int* __restrict__ pcnt)
{
    const int row0 = blockIdx.y * 128;      // global padded-row index
    int e = 0;
    #pragma unroll
    for (int i = 1; i < En; ++i) if (row0 >= off[i]) e = i;
    if (row0 >= off[e] + pcnt[e]) return;   // beyond total padded rows
    const int nt = blockIdx.x;

    const unsigned short* A = Ab + (size_t)row0 * 2048;
    const unsigned short* Bsel = (EPI == 0 && blockIdx.z) ? Bb1 : Bb0;
    const unsigned short* B = Bsel + (size_t)e * 2048 * 2048 + (size_t)nt * 128 * 2048;

    __shared__ __align__(16) unsigned short As[128 * 64];
    __shared__ __align__(16) unsigned short Bs[128 * 64];

    const int tid = threadIdx.x;
    const int lane = tid & 63;
    const int wv = tid >> 6;
    const int wm = wv & 1, wn = wv >> 1;
    const int quad = lane >> 4, l16 = lane & 15;

    f32x4 acc[4][4];
    const f32x4 zero4 = {0.f, 0.f, 0.f, 0.f};
    #pragma unroll
    for (int i = 0; i < 4; ++i)
        #pragma unroll
        for (int j = 0; j < 4; ++j) acc[i][j] = zero4;

    for (int kt = 0; kt < 2048; kt += 64) {
        __syncthreads();
        #pragma unroll
        for (int i = 0; i < 4; ++i) {
            const int grp = i * 4 + wv;
            const int idx = grp * 64 + lane;
            const int r = idx >> 3;
            const int kc = (idx & 7) ^ (r & 7);     // XOR swizzle of 16B chunks
            const unsigned short* ga = A + (size_t)r * 2048 + kt + kc * 8;
            __builtin_amdgcn_global_load_lds((const gas_u32*)ga,
                                             (las_u32*)(As + grp * 512), 16, 0, 0);
            const unsigned short* gb = B + (size_t)r * 2048 + kt + kc * 8;
            __builtin_amdgcn_global_load_lds((const gas_u32*)gb,
                                             (las_u32*)(Bs + grp * 512), 16, 0, 0);
        }
        __syncthreads();
        #pragma unroll
        for (int ks = 0; ks < 2; ++ks) {
            bf16x8 af[4], bfr[4];
            #pragma unroll
            for (int mi = 0; mi < 4; ++mi) {
                const int m = wm * 64 + mi * 16 + l16;
                const int ck = ks * 4 + quad;
                const int slot = m * 8 + (ck ^ (m & 7));
                af[mi] = *(const bf16x8*)(As + slot * 8);
            }
            #pragma unroll
            for (int ni = 0; ni < 4; ++ni) {
                const int n = wn * 64 + ni * 16 + l16;
                const int ck = ks * 4 + quad;
                const int slot = n * 8 + (ck ^ (n & 7));
                bfr[ni] = *(const bf16x8*)(Bs + slot * 8);
            }
            #pragma unroll
            for (int mi = 0; mi < 4; ++mi)
                #pragma unroll
                for (int ni = 0; ni < 4; ++ni)
                    acc[mi][ni] = __builtin_amdgcn_mfma_f32_16x16x32_bf16(
                        af[mi], bfr[ni], acc[mi][ni], 0, 0, 0);
        }
    }

    if (EPI == 0) {
        unsigned short* C = blockIdx.z ? C1 : C0;
        #pragma unroll
        for (int mi = 0; mi < 4; ++mi) {
            const int rbase = row0 + wm * 64 + mi * 16 + quad * 4;
            #pragma unroll
            for (int ni = 0; ni < 4; ++ni) {
                const int col = nt * 128 + wn * 64 + ni * 16 + l16;
                #pragma unroll
                for (int r = 0; r < 4; ++r)
                    C[(size_t)(rbase + r) * 2048 + col] = f2bf(acc[mi][ni][r]);
            }
        }
    } else {
        #pragma unroll
        for (int mi = 0; mi < 4; ++mi) {
            const int rbase = row0 + wm * 64 + mi * 16 + quad * 4;
            #pragma unroll
            for (int ni = 0; ni < 4; ++ni) {
                const int col = nt * 128 + wn * 64 + ni * 16 + l16;
                #pragma unroll
                for (int r = 0; r < 4; ++r)
                    Cf[(size_t)(rbase + r) * 2048 + col] = acc[mi][ni][r];
            }
        }
    }
}

// ---------------- G = silu(h1) * h3 (in place into H1 buffer) --------------
__global__ __launch_bounds__(256) void silumul_kernel(
    unsigned short* __restrict__ H1buf, const unsigned short* __restrict__ H3buf)
{
    const size_t idx = ((size_t)blockIdx.x * 256 + threadIdx.x) * 8;
    uint4 h1 = *(const uint4*)(H1buf + idx);
    const uint4 h3 = *(const uint4*)(H3buf + idx);
    unsigned short* p1 = (unsigned short*)&h1;
    const unsigned short* p3 = (const unsigned short*)&h3;
    #pragma unroll
    for (int j = 0; j < 8; ++j) {
        const float a = bf2f(p1[j]);
        const float b = bf2f(p3[j]);
        const float s = a / (1.f + expf(-a));
        p1[j] = f2bf(s * b);
    }
    *(uint4*)(H1buf + idx) = h1;
}

// ---------------- Merge: out[t] = wA*Yg[rowA] + wB*Yg[rowB] ----------------
__global__ __launch_bounds__(256) void merge_kernel(
    const float* __restrict__ Yg, const int* __restrict__ topi,
    const float* __restrict__ topw, const int* __restrict__ off,
    const int* __restrict__ posbuf, float* __restrict__ out)
{
    const int t = blockIdx.x;
    const int rowA = off[topi[2 * t]] + posbuf[2 * t];
    const int rowB = off[topi[2 * t + 1]] + posbuf[2 * t + 1];
    const float wA = topw[2 * t], wB = topw[2 * t + 1];
    const int c = threadIdx.x * 8;
    const float4* pa = (const float4*)(Yg + (size_t)rowA * 2048 + c);
    const float4* pb = (const float4*)(Yg + (size_t)rowB * 2048 + c);
    float4* po = (float4*)(out + (size_t)t * 2048 + c);
    #pragma unroll
    for (int i = 0; i < 2; ++i) {
        const float4 a = pa[i], b = pb[i];
        float4 o;
        o.x = wA * a.x + wB * b.x;
        o.y = wA * a.y + wB * b.y;
        o.z = wA * a.z + wB * b.z;
        o.w = wA * a.w + wB * b.w;
        po[i] = o;
    }
}

// ---------------- Workspace layout ------------------------------------------
static constexpr size_t SZ_WT  = (size_t)En * 2048 * 2048 * 2;  // 64 MiB each
static constexpr size_t SZ_XG  = (size_t)Rcap * 2048 * 2;       // 36 MiB each
static constexpr size_t O_W1T  = 0;
static constexpr size_t O_W3T  = O_W1T + SZ_WT;
static constexpr size_t O_W2T  = O_W3T + SZ_WT;
static constexpr size_t O_XG   = O_W2T + SZ_WT;
static constexpr size_t O_H1   = O_XG + SZ_XG;
static constexpr size_t O_H3   = O_H1 + SZ_XG;
static constexpr size_t O_TOPI = O_H3 + SZ_XG;
static constexpr size_t O_TOPW = O_TOPI + (size_t)Tt * 2 * 4;
static constexpr size_t O_POS  = O_TOPW + (size_t)Tt * 2 * 4;
static constexpr size_t O_OFF  = O_POS + (size_t)Tt * 2 * 4;
static constexpr size_t O_PCNT = O_OFF + 64;
static constexpr size_t O_CNT  = O_PCNT + 64;
// Yg (fp32, Rcap x 2048 = 72 MiB) aliases W1T+W3T (128 MiB), which are dead
// by the time gemm<1> runs; stream order protects across graph replays.

extern "C" void kernel_launch(void* const* d_in, const int* in_sizes, int n_in,
                              void* d_out, int out_size, void* d_ws, size_t ws_size,
                              hipStream_t stream)
{
    const float* x    = (const float*)d_in[0];
    const float* gate = (const float*)d_in[1];
    const float* w1s  = (const float*)d_in[2];
    const float* w2s  = (const float*)d_in[3];
    const float* w3s  = (const float*)d_in[4];
    float* out = (float*)d_out;
    char* ws = (char*)d_ws;

    unsigned short* w1T = (unsigned short*)(ws + O_W1T);
    unsigned short* w3T = (unsigned short*)(ws + O_W3T);
    unsigned short* w2T = (unsigned short*)(ws + O_W2T);
    unsigned short* Xg  = (unsigned short*)(ws + O_XG);
    unsigned short* H1  = (unsigned short*)(ws + O_H1);
    unsigned short* H3  = (unsigned short*)(ws + O_H3);
    float* Yg     = (float*)(ws + O_W1T);
    int*   topi   = (int*)(ws + O_TOPI);
    float* topw   = (float*)(ws + O_TOPW);
    int*   posbuf = (int*)(ws + O_POS);
    int*   off    = (int*)(ws + O_OFF);
    int*   pcnt   = (int*)(ws + O_PCNT);
    int*   cnt    = (int*)(ws + O_CNT);

    hipMemsetAsync(ws + O_XG, 0, SZ_XG, stream);           // pad rows read as 0
    hipMemsetAsync(ws + O_CNT, 0, 64, stream);             // cnt

    transpose_kernel<<<dim3(32, 32, 24), 256, 0, stream>>>(w1s, w3s, w2s, w1T, w3T, w2T);
    router_kernel<<<Tt, 256, 0, stream>>>(x, gate, topi, topw);
    assign_kernel<<<(Tt * 2) / 256, 256, 0, stream>>>(topi, cnt, posbuf);
    scan_kernel<<<1, 64, 0, stream>>>(cnt, off, pcnt);
    gather_kernel<<<Tt * 2, 256, 0, stream>>>(x, topi, off, posbuf, Xg);

    // h1 = Xg*W1^T (z=0), h3 = Xg*W3^T (z=1)
    gemm_kernel<0><<<dim3(16, 72, 2), 256, 0, stream>>>(
        Xg, w1T, w3T, H1, H3, nullptr, off, pcnt);
    // G = silu(h1)*h3, in place into H1
    silumul_kernel<<<(Rcap * Fd) / 2048, 256, 0, stream>>>(H1, H3);
    // Yg[row] = G * W2^T  (fp32, no atomics)
    gemm_kernel<1><<<dim3(16, 72, 1), 256, 0, stream>>>(
        H1, w2T, nullptr, nullptr, nullptr, Yg, off, pcnt);
    // out[t] = wA*Yg[rowA] + wB*Yg[rowB]
    merge_kernel<<<Tt, 256, 0, stream>>>(Yg, topi, topw, off, posbuf, out);
}